// Round 1
// baseline (302.211 us; speedup 1.0000x reference)
//
#include <hip/hip_runtime.h>
#include <math.h>

#define BS 2
#define QLEN 64
#define KLEN 64
#define NH 8
#define DKV 64
#define INNER 512
#define VOCAB 4096

// ---------------- workspace layout (bytes) ----------------
// qp  : [BS][QLEN][INNER] double   @ 0        (512 KB)
// kp  : [BS][KLEN][INNER] double   @ 512 KB   (512 KB)
// dnt : [DKV][VOCAB]      double   @ 1 MB     (2 MB)   (l2-normalized dict, transposed)
// E   : [VOCAB][DKV]      float    @ 3 MB     (1 MB)   (LN(dict) @ vq_o_w)
// qn2 : [BS][QLEN][NH]    double   @ 4 MB     (8 KB)
// kn2 : [BS][KLEN][NH]    double   @ 4 MB+8K  (8 KB)
// G   : [BS][NH][QLEN][KLEN] double @ ~4 MB+16K (512 KB)
// qs  : [BS][QLEN][NH][VOCAB] double @ 8 MB   (32 MB)
// ks  : [BS][KLEN][NH][VOCAB] double @ 40 MB  (32 MB)
// total = 72 MB

// q_proj / k_proj rows in fp64:  out[b,r,e] = sum_d (in+pos)[b,r,d] * wi[d(+512),e]
__global__ void k_proj(const float* __restrict__ q_in, const float* __restrict__ k_in,
                       const float* __restrict__ qpe, const float* __restrict__ kpe,
                       const float* __restrict__ wi,
                       double* __restrict__ qp, double* __restrict__ kp)
{
    int bid = blockIdx.x;            // 256 blocks
    int which = bid >> 7;            // 0 = q, 1 = k
    int rem = bid & 127;
    int b = rem >> 6, r = rem & 63;
    const float* xin = which ? k_in : q_in;
    const float* pin = which ? kpe : qpe;
    double* outp = which ? kp : qp;
    int wrow0 = which ? INNER : 0;

    __shared__ double xs[INNER];
    int t = threadIdx.x;
    int rowoff = (b * QLEN + r) * INNER;
    for (int d = t; d < INNER; d += 256)
        xs[d] = (double)xin[rowoff + d] + (double)pin[rowoff + d];
    __syncthreads();
    int e0 = t, e1 = t + 256;
    double a0 = 0.0, a1 = 0.0;
    for (int d = 0; d < INNER; ++d) {
        double x = xs[d];
        const float* wr = wi + (size_t)(wrow0 + d) * INNER;
        a0 = fma(x, (double)wr[e0], a0);
        a1 = fma(x, (double)wr[e1], a1);
    }
    outp[rowoff + e0] = a0;
    outp[rowoff + e1] = a1;
}

// per-vocab-row: l2norm (transposed store) + E = LN(row) @ vq_o_w
__global__ void k_dict(const float* __restrict__ vq, const float* __restrict__ g,
                       const float* __restrict__ bta, const float* __restrict__ ow,
                       double* __restrict__ dnt, float* __restrict__ E)
{
    int v = blockIdx.x;           // 4096 blocks, 64 threads (one wave)
    int j = threadIdx.x;
    double z = (double)vq[v * DKV + j];
    double s2 = z * z, s1 = z;
    for (int m = 32; m >= 1; m >>= 1) { s2 += __shfl_xor(s2, m); s1 += __shfl_xor(s1, m); }
    double dn = z * (1.0 / sqrt(fmax(s2, 1e-12)));
    dnt[j * VOCAB + v] = dn;
    double mean = s1 * (1.0 / 64.0);
    double d0 = z - mean;
    double vv = d0 * d0;
    for (int m = 32; m >= 1; m >>= 1) vv += __shfl_xor(vv, m);
    vv *= (1.0 / 64.0);
    double ln = d0 * (1.0 / sqrt(vv + 1e-6)) * (double)g[j] + (double)bta[j];
    __shared__ double lns[DKV];
    lns[j] = ln;
    __syncthreads();
    double acc = 0.0;                 // thread index acts as output column e
    for (int jj = 0; jj < DKV; ++jj)
        acc = fma(lns[jj], (double)ow[jj * DKV + j], acc);
    E[v * DKV + j] = (float)acc;
}

// per (b,h): qn2[q], kn2[k], Gram G[q][k] = qp_h[q] . kp_h[k]
__global__ void k_gram(const double* __restrict__ qp, const double* __restrict__ kp,
                       double* __restrict__ qn2, double* __restrict__ kn2,
                       double* __restrict__ G)
{
    int bh = blockIdx.x;            // 16 blocks
    int b = bh >> 3, h = bh & 7;
    __shared__ double qph[QLEN][DKV + 1];
    __shared__ double kph[KLEN][DKV + 1];
    int t = threadIdx.x;
    for (int idx = t; idx < QLEN * DKV; idx += 256) {
        int r = idx >> 6, j = idx & 63;
        qph[r][j] = qp[(b * QLEN + r) * INNER + h * DKV + j];
        kph[r][j] = kp[(b * KLEN + r) * INNER + h * DKV + j];
    }
    __syncthreads();
    if (t < 64) {
        double s = 0.0;
        for (int j = 0; j < DKV; ++j) s = fma(qph[t][j], qph[t][j], s);
        qn2[(b * QLEN + t) * NH + h] = s;
    } else if (t < 128) {
        int k = t - 64;
        double s = 0.0;
        for (int j = 0; j < DKV; ++j) s = fma(kph[k][j], kph[k][j], s);
        kn2[(b * KLEN + k) * NH + h] = s;
    }
    for (int p = t; p < QLEN * KLEN; p += 256) {
        int q = p >> 6, k = p & 63;
        double s = 0.0;
        for (int j = 0; j < DKV; ++j) s = fma(qph[q][j], kph[k][j], s);
        G[(bh * QLEN + q) * KLEN + k] = s;
    }
}

// qs[b,row,h,v] = qp_head . d_n[v]   (and same for ks) in fp64
__global__ void k_sim(const double* __restrict__ qp, const double* __restrict__ kp,
                      const double* __restrict__ dnt,
                      double* __restrict__ qs, double* __restrict__ ks)
{
    int bid = blockIdx.x;           // 256 blocks
    int which = bid >> 7;
    int rem = bid & 127;
    int b = rem >> 6, r = rem & 63;
    const double* src = (which ? kp : qp) + (size_t)(b * 64 + r) * INNER;
    double* dst = (which ? ks : qs) + (size_t)(b * 64 + r) * NH * VOCAB;
    __shared__ double xs[INNER];
    int t = threadIdx.x;
    for (int d = t; d < INNER; d += 256) xs[d] = src[d];
    __syncthreads();
    for (int i = 0; i < 4; ++i) {
        int v0 = t + 1024 * i;
        double acc[4][8];
        #pragma unroll
        for (int m = 0; m < 4; ++m)
            #pragma unroll
            for (int h = 0; h < 8; ++h) acc[m][h] = 0.0;
        for (int j = 0; j < DKV; ++j) {
            const double* dr = dnt + j * VOCAB;
            double dv0 = dr[v0], dv1 = dr[v0 + 256], dv2 = dr[v0 + 512], dv3 = dr[v0 + 768];
            #pragma unroll
            for (int h = 0; h < 8; ++h) {
                double x = xs[h * DKV + j];
                acc[0][h] = fma(x, dv0, acc[0][h]);
                acc[1][h] = fma(x, dv1, acc[1][h]);
                acc[2][h] = fma(x, dv2, acc[2][h]);
                acc[3][h] = fma(x, dv3, acc[3][h]);
            }
        }
        #pragma unroll
        for (int m = 0; m < 4; ++m)
            #pragma unroll
            for (int h = 0; h < 8; ++h)
                dst[h * VOCAB + v0 + m * 256] = acc[m][h];
    }
}

// hot kernel: per (b,h,q-pair): argmax_v(qs+ks) for all 64 k, word_sim,
// outputs ids/scores, weighted mean over k, final layernorm
__global__ void __launch_bounds__(256) k_argmax(
    const double* __restrict__ qs, const double* __restrict__ ks,
    const double* __restrict__ qn2, const double* __restrict__ kn2,
    const double* __restrict__ G, const float* __restrict__ E,
    const float* __restrict__ lng, const float* __restrict__ lnb,
    float* __restrict__ out)
{
    int bid = blockIdx.x;            // 512 blocks = b*256 + h*32 + qpair
    int qpair = bid & 31;
    int h = (bid >> 5) & 7;
    int b = bid >> 8;
    int q0 = qpair * 2;

    __shared__ double qsl[2][VOCAB];          // 64 KB
    __shared__ double bestv_l[2][KLEN];
    __shared__ int    besti_l[2][KLEN];
    __shared__ double ws_l[2][KLEN];

    int t = threadIdx.x;
    for (int i = t; i < 2 * VOCAB; i += 256) {
        int qq = i >> 12;
        int v = i & (VOCAB - 1);
        qsl[qq][v] = qs[((size_t)(b * QLEN + q0 + qq) * NH + h) * VOCAB + v];
    }
    __syncthreads();

    int wave = t >> 6, lane = t & 63;
    for (int kk = 0; kk < 16; ++kk) {
        int k = wave + 4 * kk;
        const double* kr = ks + ((size_t)(b * KLEN + k) * NH + h) * VOCAB;
        double b0 = -1e300, b1 = -1e300;
        int i0 = 0, i1 = 0;
        for (int it = 0; it < 64; ++it) {
            int v = lane + 64 * it;
            double kv = kr[v];
            double v0 = qsl[0][v] + kv;
            double v1 = qsl[1][v] + kv;
            if (v0 > b0) { b0 = v0; i0 = v; }
            if (v1 > b1) { b1 = v1; i1 = v; }
        }
        // intra-wave argmax reduce, ties -> smaller index (numpy argmax semantics)
        for (int m = 1; m < 64; m <<= 1) {
            double ov = __shfl_xor(b0, m); int oi = __shfl_xor(i0, m);
            if (ov > b0 || (ov == b0 && oi < i0)) { b0 = ov; i0 = oi; }
            ov = __shfl_xor(b1, m); oi = __shfl_xor(i1, m);
            if (ov > b1 || (ov == b1 && oi < i1)) { b1 = ov; i1 = oi; }
        }
        if (lane == 0) {
            bestv_l[0][k] = b0; besti_l[0][k] = i0;
            bestv_l[1][k] = b1; besti_l[1][k] = i1;
        }
    }
    __syncthreads();

    if (t < 128) {
        int qi = t >> 6, k = t & 63;
        int q = q0 + qi;
        double n2 = qn2[(b * QLEN + q) * NH + h] + kn2[(b * KLEN + k) * NH + h]
                  + 2.0 * G[(((size_t)b * NH + h) * QLEN + q) * KLEN + k];
        double wsim = bestv_l[qi][k] * (1.0 / sqrt(fmax(n2, 1e-12)));
        ws_l[qi][k] = wsim;
        size_t oidx = ((size_t)(b * QLEN + q) * KLEN + k) * NH + h;
        out[65536 + oidx] = (float)besti_l[qi][k];   // out_ids as float32
        out[131072 + oidx] = (float)wsim;            // r3_scores
    }
    __syncthreads();

    if (t < 128) {
        int qi = t >> 6, d = t & 63;
        int q = q0 + qi;
        float acc = 0.0f;
        for (int k = 0; k < KLEN; ++k)
            acc += E[besti_l[qi][k] * DKV + d] * (float)ws_l[qi][k];
        acc *= (1.0f / 64.0f);                       // mean over klen
        // layernorm across d (one wave holds one q-row)
        float mean = acc;
        for (int m = 32; m >= 1; m >>= 1) mean += __shfl_xor(mean, m);
        mean *= (1.0f / 64.0f);
        float dv = acc - mean;
        float var = dv * dv;
        for (int m = 32; m >= 1; m >>= 1) var += __shfl_xor(var, m);
        var *= (1.0f / 64.0f);
        float o = dv * rsqrtf(var + 1e-6f) * lng[d] + lnb[d];
        out[(((size_t)b * NH + h) * QLEN + q) * DKV + d] = o;
    }
}

extern "C" void kernel_launch(void* const* d_in, const int* in_sizes, int n_in,
                              void* d_out, int out_size, void* d_ws, size_t ws_size,
                              hipStream_t stream) {
    const float* query = (const float*)d_in[0];
    const float* key   = (const float*)d_in[1];
    const float* qpe   = (const float*)d_in[2];
    const float* kpe   = (const float*)d_in[3];
    const float* wi    = (const float*)d_in[4];
    const float* vq    = (const float*)d_in[5];
    const float* vqg   = (const float*)d_in[6];
    const float* vqb   = (const float*)d_in[7];
    const float* ow    = (const float*)d_in[8];
    const float* lng   = (const float*)d_in[9];
    const float* lnb   = (const float*)d_in[10];
    float* out = (float*)d_out;

    char* ws = (char*)d_ws;
    double* qp  = (double*)(ws + 0);
    double* kp  = (double*)(ws + 524288);
    double* dnt = (double*)(ws + 1048576);
    float*  E   = (float*) (ws + 3145728);
    double* qn2 = (double*)(ws + 4194304);
    double* kn2 = (double*)(ws + 4202496);
    double* G   = (double*)(ws + 4210688);
    double* qs  = (double*)(ws + 8388608);
    double* ks  = (double*)(ws + 41943040);

    k_proj  <<<256, 256, 0, stream>>>(query, key, qpe, kpe, wi, qp, kp);
    k_dict  <<<4096, 64, 0, stream>>>(vq, vqg, vqb, ow, dnt, E);
    k_gram  <<<16, 256, 0, stream>>>(qp, kp, qn2, kn2, G);
    k_sim   <<<256, 256, 0, stream>>>(qp, kp, dnt, qs, ks);
    k_argmax<<<512, 256, 0, stream>>>(qs, ks, qn2, kn2, G, E, lng, lnb, out);
}